// Round 1
// baseline (152.945 us; speedup 1.0000x reference)
//
#include <hip/hip_runtime.h>

#define H2    1024
#define LSRC  1024
#define BATCH 64

__device__ __forceinline__ float fast_tanh(float x) {
  // tanh(x) = 1 - 2/(exp(2x)+1); saturates correctly for |x| large.
  float e2 = __expf(2.0f * x);
  return 1.0f - 2.0f / (e2 + 1.0f);
}

// dec[b][h] = sum_k s[b][k] * W[h][k] + bias[h]   (s: [64,1024], W: [1024,1024])
// grid = 64 blocks (16 h each), block = 256. LDS-tiled over k.
__global__ __launch_bounds__(256) void dec_kernel(
    const float* __restrict__ s, const float* __restrict__ W,
    const float* __restrict__ bias, float* __restrict__ dec) {
  const int KT = 128;
  __shared__ float s_lds[BATCH][KT + 1];  // +1 pad: lane-varying bi reads hit all banks
  __shared__ float w_lds[16][KT];         // broadcast reads, no pad needed
  const int t  = threadIdx.x;
  const int h0 = blockIdx.x * 16;
  const int bi = t & 63;
  const int hg = t >> 6;  // 0..3
  float acc[4] = {0.f, 0.f, 0.f, 0.f};
  for (int k0 = 0; k0 < H2; k0 += KT) {
    __syncthreads();
    for (int idx = t; idx < BATCH * KT; idx += 256) {
      int r = idx >> 7, c = idx & (KT - 1);
      s_lds[r][c] = s[r * H2 + k0 + c];
    }
    for (int idx = t; idx < 16 * KT; idx += 256) {
      int r = idx >> 7, c = idx & (KT - 1);
      w_lds[r][c] = W[(h0 + r) * H2 + k0 + c];
    }
    __syncthreads();
    for (int k = 0; k < KT; ++k) {
      float sv = s_lds[bi][k];
#pragma unroll
      for (int j = 0; j < 4; ++j) acc[j] += sv * w_lds[hg + 4 * j][k];
    }
  }
#pragma unroll
  for (int j = 0; j < 4; ++j) {
    int h = h0 + hg + 4 * j;
    dec[bi * H2 + h] = acc[j] + bias[h];
  }
}

// e[row] = sum_h tanh(ef[row][h] + dec[b][h]) * v[h]; one wave per row.
__global__ __launch_bounds__(256) void e_kernel(
    const float* __restrict__ ef, const float* __restrict__ dec,
    const float* __restrict__ v, float* __restrict__ e) {
  const int lane = threadIdx.x & 63;
  const int wave = threadIdx.x >> 6;
  const int row  = blockIdx.x * 4 + wave;  // 0..65535
  const int b    = row >> 10;
  const float4* ef4  = (const float4*)(ef) + (size_t)row * 256;
  const float4* dec4 = (const float4*)(dec) + (size_t)b * 256;
  const float4* v4   = (const float4*)(v);
  float sum = 0.f;
#pragma unroll
  for (int i = 0; i < 4; ++i) {
    int idx = lane + 64 * i;       // coalesced: 16B/lane contiguous
    float4 x  = ef4[idx];
    float4 d  = dec4[idx];
    float4 vv = v4[idx];
    sum += fast_tanh(x.x + d.x) * vv.x;
    sum += fast_tanh(x.y + d.y) * vv.y;
    sum += fast_tanh(x.z + d.z) * vv.z;
    sum += fast_tanh(x.w + d.w) * vv.w;
  }
#pragma unroll
  for (int off = 32; off; off >>= 1) sum += __shfl_xor(sum, off);
  if (lane == 0) e[row] = sum;
}

// attn[b][l] = exp(e-m)*mask / sum(exp(e-m)*mask)  — identical to
// softmax(e)*mask renormalized (denominators cancel). One block per b.
__global__ __launch_bounds__(256) void softmax_kernel(
    const float* __restrict__ e, const float* __restrict__ mask,
    float* __restrict__ attn) {
  __shared__ float wmax[4], wsum[4];
  const int b = blockIdx.x, t = threadIdx.x;
  const int lane = t & 63, wave = t >> 6;
  float4 ev = ((const float4*)(e + b * LSRC))[t];
  float4 mk = ((const float4*)(mask + b * LSRC))[t];
  float m = fmaxf(fmaxf(ev.x, ev.y), fmaxf(ev.z, ev.w));
#pragma unroll
  for (int off = 32; off; off >>= 1) m = fmaxf(m, __shfl_xor(m, off));
  if (lane == 0) wmax[wave] = m;
  __syncthreads();
  m = fmaxf(fmaxf(wmax[0], wmax[1]), fmaxf(wmax[2], wmax[3]));
  float e0 = __expf(ev.x - m) * mk.x;
  float e1 = __expf(ev.y - m) * mk.y;
  float e2 = __expf(ev.z - m) * mk.z;
  float e3 = __expf(ev.w - m) * mk.w;
  float ssum = e0 + e1 + e2 + e3;
#pragma unroll
  for (int off = 32; off; off >>= 1) ssum += __shfl_xor(ssum, off);
  if (lane == 0) wsum[wave] = ssum;
  __syncthreads();
  float inv = 1.0f / (wsum[0] + wsum[1] + wsum[2] + wsum[3]);
  float4 o = {e0 * inv, e1 * inv, e2 * inv, e3 * inv};
  ((float4*)(attn + b * LSRC))[t] = o;
}

// part[lc][b][h] = sum_{l in chunk lc} attn[b][l] * eo[b][l][h]
// grid = (8 l-chunks, 64 b); thread t owns float4 at h = 4t.
__global__ __launch_bounds__(256) void ct_partial_kernel(
    const float* __restrict__ attn, const float* __restrict__ eo,
    float* __restrict__ part) {
  const int lc = blockIdx.x;  // 0..7
  const int b  = blockIdx.y;  // 0..63
  const int t  = threadIdx.x;
  const float*  ab  = attn + b * LSRC;
  const float4* eob = (const float4*)(eo) + (size_t)b * LSRC * 256;
  float4 acc = {0.f, 0.f, 0.f, 0.f};
  const int l0 = lc * (LSRC / 8);
#pragma unroll 4
  for (int l = l0; l < l0 + LSRC / 8; ++l) {
    float  a = ab[l];                       // block-uniform -> scalar load
    float4 x = eob[(size_t)l * 256 + t];    // coalesced 1KB/wave
    acc.x += a * x.x; acc.y += a * x.y; acc.z += a * x.z; acc.w += a * x.w;
  }
  ((float4*)(part) + (size_t)(lc * BATCH + b) * 256)[t] = acc;
}

// out[b][h] = sum_lc part[lc][b][h]
__global__ __launch_bounds__(256) void reduce_kernel(
    const float* __restrict__ part, float* __restrict__ out) {
  const int b = blockIdx.x, t = threadIdx.x;
  float4 s = {0.f, 0.f, 0.f, 0.f};
#pragma unroll
  for (int lc = 0; lc < 8; ++lc) {
    float4 x = ((const float4*)(part) + (size_t)(lc * BATCH + b) * 256)[t];
    s.x += x.x; s.y += x.y; s.z += x.z; s.w += x.w;
  }
  ((float4*)(out) + (size_t)b * 256)[t] = s;
}

extern "C" void kernel_launch(void* const* d_in, const int* in_sizes, int n_in,
                              void* d_out, int out_size, void* d_ws, size_t ws_size,
                              hipStream_t stream) {
  const float* s_t_hat  = (const float*)d_in[0];
  const float* enc_out  = (const float*)d_in[1];
  const float* enc_feat = (const float*)d_in[2];
  const float* mask     = (const float*)d_in[3];
  const float* W        = (const float*)d_in[4];
  const float* bias     = (const float*)d_in[5];
  const float* v        = (const float*)d_in[6];
  float* out = (float*)d_out;

  // workspace layout (fp32): dec[64*1024] | e[64*1024] | attn[64*1024] | part[8*64*1024]
  float* dec  = (float*)d_ws;
  float* e    = dec  + BATCH * H2;
  float* attn = e    + BATCH * LSRC;
  float* part = attn + BATCH * LSRC;

  dec_kernel<<<H2 / 16, 256, 0, stream>>>(s_t_hat, W, bias, dec);
  e_kernel<<<(BATCH * LSRC) / 4, 256, 0, stream>>>(enc_feat, dec, v, e);
  softmax_kernel<<<BATCH, 256, 0, stream>>>(e, mask, attn);
  ct_partial_kernel<<<dim3(8, BATCH), 256, 0, stream>>>(attn, enc_out, part);
  reduce_kernel<<<BATCH, 256, 0, stream>>>(part, out);
}